// Round 11
// baseline (212.991 us; speedup 1.0000x reference)
//
#include <hip/hip_runtime.h>

// GraphAttention fused forward for MI355X (gfx950).
// MFMA PV; packed bf16 adj+msk LDS staging (1 dword/element), 4 i-rows/lane.
// B=4, N=2048, F=64, FP=32, H=4.  Output: [B,N,H*FP] f32 ++ uloss ++ eloss.

#define B_ 4
#define N_ 2048
#define F_ 64
#define FP_ 32
#define H_ 4
#define C_ 128
#define IT_ 64                 // i-rows per attn block (4 per lane)
#define ITILES_ (N_ / IT_)     // 32
#define JCA_ 8                 // j-chunks -> grid 1024 = 4 blocks/CU
#define JSPANA_ (N_ / JCA_)    // 256
#define JST_ 64                // j per LDS stage
#define NST_ (JSPANA_ / JST_)  // 4 stages
#define KCS_ (JST_ / 32)       // 2 MFMA k-steps per stage
#define APAD_ 66               // dword stride: b64 @ (2r+8q)%32 = uniform 4/bank = free

typedef __attribute__((ext_vector_type(8))) short short8v;   // 8 bf16 = 4 VGPRs
typedef __attribute__((ext_vector_type(4))) float f32x4;     // MFMA C/D
typedef __attribute__((ext_vector_type(4))) int   int4v;
typedef __attribute__((ext_vector_type(2))) int   int2v;

union PkU { int4v i; short8v s; };

__device__ __forceinline__ unsigned short f2bf(float f) {    // RNE fp32->bf16
    unsigned u = __float_as_uint(f);
    u += 0x7fffu + ((u >> 16) & 1u);
    return (unsigned short)(u >> 16);
}

// pack (adj,msk) -> [msk.hi16 | adj.hi16], half-up rounded
__device__ __forceinline__ int pkpair(float a, float m) {
    return (int)__builtin_amdgcn_perm(__float_as_uint(m) + 0x8000u,
                                      __float_as_uint(a) + 0x8000u, 0x07060302u);
}

// 8 packed elements -> l,A accumulate + packed bf16 A-frag dword x4.
__device__ __forceinline__ void attn_qstep_pk(
    float si, int4v pa, int4v pb, const float* tv,
    float& l, float& A, int4v& apk)
{
#pragma unroll
    for (int qq = 0; qq < 4; ++qq) {
        int d0 = (qq < 2) ? pa[2 * qq]     : pb[2 * qq - 4];
        int d1 = (qq < 2) ? pa[2 * qq + 1] : pb[2 * qq - 3];
        float a0 = __uint_as_float((unsigned)d0 << 16);
        float m0 = __uint_as_float((unsigned)d0 & 0xffff0000u);
        float a1 = __uint_as_float((unsigned)d1 << 16);
        float m1 = __uint_as_float((unsigned)d1 & 0xffff0000u);
        float dv0 = si + tv[2 * qq];
        dv0 = fmaxf(dv0, 0.2f * dv0) + m0;            // LeakyReLU(0.2) + mask
        float e0 = __expf(dv0);                       // bounded: no max-subtract
        float p0 = e0 * a0;
        float dv1 = si + tv[2 * qq + 1];
        dv1 = fmaxf(dv1, 0.2f * dv1) + m1;
        float e1 = __expf(dv1);
        float p1 = e1 * a1;
        l += e0 + e1;
        A += p0 + p1;
        unsigned u0 = __float_as_uint(p0) + 0x8000u;
        unsigned u1 = __float_as_uint(p1) + 0x8000u;
        apk[qq] = (int)__builtin_amdgcn_perm(u1, u0, 0x07060302u); // [p1.hi|p0.hi]
    }
}

// ---------------------------------------------------------------- kernel 1
// feats = x@W per head via MFMA; writes featsT bf16 [b][h][d][n] + s,t fp32.
// Also zero-inits the two loss slots of out (stream order precedes final).
__global__ __launch_bounds__(256) void prep_kernel(
    const float* __restrict__ x, const float* __restrict__ W,
    const float* __restrict__ a_self, const float* __restrict__ a_neigh,
    unsigned short* __restrict__ featsT, float* __restrict__ sbuf,
    float* __restrict__ tbuf, float* __restrict__ out)
{
    int blk = blockIdx.x;              // b*32 + nt
    int b = blk >> 5, nt = blk & 31;
    int n0 = nt << 6;
    int t = threadIdx.x, h = t >> 6, lane = t & 63;
    int quad = lane >> 4, col = lane & 15;
    if (blk == 0 && t == 0) {
        out[(size_t)B_ * N_ * C_]     = 0.f;   // uloss == 0 identically
        out[(size_t)B_ * N_ * C_ + 1] = 0.f;   // eloss accumulated by final
    }

    short8v bw[2][2];
    const float* Wh = W + (size_t)h * F_ * FP_;
#pragma unroll
    for (int kc = 0; kc < 2; ++kc)
#pragma unroll
        for (int dt = 0; dt < 2; ++dt)
#pragma unroll
            for (int e = 0; e < 8; ++e) {
                int f = kc * 32 + quad * 8 + e;
                bw[kc][dt][e] = (short)f2bf(Wh[f * FP_ + dt * 16 + col]);
            }
    float as0 = a_self[h * FP_ + col],  as1 = a_self[h * FP_ + 16 + col];
    float an0 = a_neigh[h * FP_ + col], an1 = a_neigh[h * FP_ + 16 + col];
    size_t hrow = ((size_t)b * H_ + h) * N_;
    size_t ftb  = ((size_t)b * H_ + h) * FP_;

    for (int ms = 0; ms < 4; ++ms) {
        int row = n0 + ms * 16 + col;          // A row m = lane&15
        const float* xr = x + ((size_t)b * N_ + row) * F_;
        f32x4 acc0 = {0.f, 0.f, 0.f, 0.f}, acc1 = {0.f, 0.f, 0.f, 0.f};
#pragma unroll
        for (int kc = 0; kc < 2; ++kc) {
            float4 x0 = *(const float4*)(xr + kc * 32 + quad * 8);
            float4 x1 = *(const float4*)(xr + kc * 32 + quad * 8 + 4);
            short8v av;
            av[0] = (short)f2bf(x0.x); av[1] = (short)f2bf(x0.y);
            av[2] = (short)f2bf(x0.z); av[3] = (short)f2bf(x0.w);
            av[4] = (short)f2bf(x1.x); av[5] = (short)f2bf(x1.y);
            av[6] = (short)f2bf(x1.z); av[7] = (short)f2bf(x1.w);
            acc0 = __builtin_amdgcn_mfma_f32_16x16x32_bf16(av, bw[kc][0], acc0, 0, 0, 0);
            acc1 = __builtin_amdgcn_mfma_f32_16x16x32_bf16(av, bw[kc][1], acc1, 0, 0, 0);
        }
        {   // C layout: row = quad*4+rr, col = lane&15 (verified m89/m91)
            ushort4 v0, v1;
            v0.x = f2bf(acc0[0]); v0.y = f2bf(acc0[1]);
            v0.z = f2bf(acc0[2]); v0.w = f2bf(acc0[3]);
            v1.x = f2bf(acc1[0]); v1.y = f2bf(acc1[1]);
            v1.z = f2bf(acc1[2]); v1.w = f2bf(acc1[3]);
            size_t nidx = (size_t)n0 + ms * 16 + quad * 4;
            *(ushort4*)(featsT + (ftb + col) * N_ + nidx)      = v0;
            *(ushort4*)(featsT + (ftb + 16 + col) * N_ + nidx) = v1;
        }
#pragma unroll
        for (int rr = 0; rr < 4; ++rr) {
            float sv = acc0[rr] * as0 + acc1[rr] * as1;
            float tv = acc0[rr] * an0 + acc1[rr] * an1;
#pragma unroll
            for (int off = 8; off; off >>= 1) {
                sv += __shfl_down(sv, off);
                tv += __shfl_down(tv, off);
            }
            if (col == 0) {
                int n = n0 + ms * 16 + quad * 4 + rr;
                sbuf[hrow + n] = sv;
                tbuf[hrow + n] = tv;
            }
        }
    }
}

// ---------------------------------------------------------------- kernel 2
// Block = (b, 64-row i-tile, jc); 4 waves = 4 heads; 4 i-rows per lane.
// adj+msk staged as ONE packed dword/element (bf16 halves) -> half the LDS
// bytes and footprint; B-frags shared across the 4 row-group MFMAs.
__global__ __launch_bounds__(256, 4) void attn_kernel(
    const float* __restrict__ adj, const float* __restrict__ msk,
    const unsigned short* __restrict__ featsT,
    const float* __restrict__ sbuf, const float* __restrict__ tbuf,
    float* __restrict__ part, float* __restrict__ lpart)
{
    __shared__ int   lds_pk[IT_ * APAD_];    // [row][j] packed (msk|adj)
    __shared__ float lds_t[H_ * JST_];

    int blk = blockIdx.x;
    int jc = blk & (JCA_ - 1);
    int it = (blk >> 3) & (ITILES_ - 1);
    int b  = blk >> 8;
    int t = threadIdx.x, h = t >> 6, lane = t & 63;
    int quad = lane >> 4, r = lane & 15;
    int i0 = it * IT_;
    int jbase = jc * JSPANA_;

    size_t hrow = ((size_t)b * H_ + h) * N_;
    float si[4];
#pragma unroll
    for (int rg = 0; rg < 4; ++rg) si[rg] = sbuf[hrow + i0 + 16 * rg + r];
    // B-frag: lane(quad,r) holds featsT[d=r][j = slice + quad*8 + e]
    const unsigned short* ft0 = featsT + (((size_t)b * H_ + h) * FP_ + r) * N_
                                + jbase + quad * 8;
    const unsigned short* ft1 = ft0 + (size_t)16 * N_;

    // staging: thread t covers rows srow+16k (k=0..3), float4 j-slot sf4
    int srow = t >> 4, sf4 = (t & 15) * 4;
    const float* adjs = adj + ((size_t)b * N_ + i0 + srow) * N_ + jbase + sf4;
    const float* msks = msk + ((size_t)b * N_ + i0 + srow) * N_ + jbase + sf4;
    int th = t >> 6, tj = t & 63;
    const float* tbs = tbuf + ((size_t)b * H_ + th) * N_ + jbase + tj;

    f32x4 acc[4][2];
#pragma unroll
    for (int rg = 0; rg < 4; ++rg)
#pragma unroll
        for (int dt = 0; dt < 2; ++dt) acc[rg][dt] = (f32x4){0.f, 0.f, 0.f, 0.f};
    float l[4] = {0.f, 0.f, 0.f, 0.f}, A[4] = {0.f, 0.f, 0.f, 0.f};

#pragma unroll
    for (int st = 0; st < NST_; ++st) {
        int j0 = st * JST_;
        __syncthreads();                       // prev compute done
#pragma unroll
        for (int k = 0; k < 4; ++k) {
            float4 a4 = *(const float4*)(adjs + (size_t)(16 * k) * N_ + j0);
            float4 m4 = *(const float4*)(msks + (size_t)(16 * k) * N_ + j0);
            int2v w0, w1;
            w0[0] = pkpair(a4.x, m4.x); w0[1] = pkpair(a4.y, m4.y);
            w1[0] = pkpair(a4.z, m4.z); w1[1] = pkpair(a4.w, m4.w);
            int* dst = &lds_pk[(srow + 16 * k) * APAD_ + sf4];
            *(int2v*)dst       = w0;           // b64: (2r+4f)%32 uniform -> free
            *(int2v*)(dst + 2) = w1;
        }
        lds_t[th * JST_ + tj] = tbs[j0];
        __syncthreads();
#pragma unroll
        for (int kc = 0; kc < KCS_; ++kc) {
            int jt = kc * 32 + quad * 8;               // col within stage
            int jl = j0 + kc * 32;                     // featsT idx (quad*8 in ptr)
            float4 t0 = *(const float4*)&lds_t[h * JST_ + jt];    // broadcast
            float4 t1 = *(const float4*)&lds_t[h * JST_ + jt + 4];
            short8v bv0 = *(const short8v*)(ft0 + jl);
            short8v bv1 = *(const short8v*)(ft1 + jl);
            float tv[8] = {t0.x, t0.y, t0.z, t0.w, t1.x, t1.y, t1.z, t1.w};
            PkU ap[4];
#pragma unroll
            for (int rg = 0; rg < 4; ++rg) {
                const int* pkrow = &lds_pk[(r + 16 * rg) * APAD_ + jt];
                int2v q0 = *(const int2v*)(pkrow);     // 4x b64, conflict-free
                int2v q1 = *(const int2v*)(pkrow + 2);
                int2v q2 = *(const int2v*)(pkrow + 4);
                int2v q3 = *(const int2v*)(pkrow + 6);
                int4v pa = {q0[0], q0[1], q1[0], q1[1]};
                int4v pb = {q2[0], q2[1], q3[0], q3[1]};
                attn_qstep_pk(si[rg], pa, pb, tv, l[rg], A[rg], ap[rg].i);
            }
#pragma unroll
            for (int rg = 0; rg < 4; ++rg) {
                acc[rg][0] = __builtin_amdgcn_mfma_f32_16x16x32_bf16(ap[rg].s, bv0, acc[rg][0], 0, 0, 0);
                acc[rg][1] = __builtin_amdgcn_mfma_f32_16x16x32_bf16(ap[rg].s, bv1, acc[rg][1], 0, 0, 0);
            }
        }
    }
    // fold 4 k-group lanes -> row totals in lanes 0-15
#pragma unroll
    for (int rg = 0; rg < 4; ++rg) {
        l[rg] += __shfl_down(l[rg], 32); l[rg] += __shfl_down(l[rg], 16);
        A[rg] += __shfl_down(A[rg], 32); A[rg] += __shfl_down(A[rg], 16);
    }

    size_t pb = (((size_t)(b * H_ + h) * ITILES_ + it) * JCA_ + jc) * 2048;
#pragma unroll
    for (int rg = 0; rg < 4; ++rg) {
        *(f32x4*)&part[pb + (rg * 2 + 0) * 256 + lane * 4] = acc[rg][0];
        *(f32x4*)&part[pb + (rg * 2 + 1) * 256 + lane * 4] = acc[rg][1];
    }
    if (lane < 16) {
        size_t lb = (((size_t)(b * H_ + h) * ITILES_ + it) * JCA_ + jc) * 128;
#pragma unroll
        for (int rg = 0; rg < 4; ++rg) {
            lpart[lb + rg * 16 + lane]      = l[rg];
            lpart[lb + 64 + rg * 16 + lane] = A[rg];
        }
    }
}

// ---------------------------------------------------------------- kernel 3
// Block = (b, 32-row half-tile). Merge jc partials, /l, bias, BN, ReLU,
// LDS transpose, coalesced out; eloss via one atomicAdd per (block,h).
__global__ __launch_bounds__(256) void final_kernel(
    const float* __restrict__ part, const float* __restrict__ lpart,
    const float* __restrict__ bias, const float* __restrict__ gamma,
    const float* __restrict__ beta, const float* __restrict__ mmean,
    const float* __restrict__ mvar, float* __restrict__ out)
{
    __shared__ float ldsl[H_ * 32];
    __shared__ float ldso[32 * 132];
    int blk = blockIdx.x;              // b*64 + ht;  ht = it*2 + half
    int b = blk >> 6, ht = blk & 63;
    int it = ht >> 1, half = ht & 1;
    int t = threadIdx.x, h = t >> 6, lane = t & 63;
    int quad = lane >> 4, col = lane & 15;

    size_t pb = (((size_t)(b * H_ + h) * ITILES_ + it) * JCA_) * 2048
                + (size_t)half * 4 * 256;
    f32x4 C[4];
#pragma unroll
    for (int k = 0; k < 4; ++k) C[k] = (f32x4){0.f, 0.f, 0.f, 0.f};
#pragma unroll
    for (int c = 0; c < JCA_; ++c)
#pragma unroll
        for (int k = 0; k < 4; ++k)
            C[k] += *(const f32x4*)&part[pb + c * 2048 + k * 256 + lane * 4];

    size_t lb = (((size_t)(b * H_ + h) * ITILES_ + it) * JCA_) * 128
                + half * 32;
    if (lane < 32) {
        float lt = 0.f, At = 0.f;
#pragma unroll
        for (int c = 0; c < JCA_; ++c) {
            lt += lpart[lb + c * 128 + lane];
            At += lpart[lb + c * 128 + 64 + lane];
        }
        ldsl[h * 32 + lane] = lt;
        float e = At / lt;
#pragma unroll
        for (int off = 16; off; off >>= 1) e += __shfl_down(e, off);
        if (lane == 0)
            atomicAdd(out + (size_t)B_ * N_ * C_ + 1, e * (1.f / N_));
    }
    __syncthreads();
#pragma unroll
    for (int dt = 0; dt < 2; ++dt) {
        int c = h * FP_ + dt * 16 + col;
        float sc = rsqrtf(mvar[c] + 1e-3f) * gamma[c];
        float sh = beta[c] - mmean[c] * sc;
        float bi = bias[c];
#pragma unroll
        for (int rr = 0; rr < 2; ++rr) {
            f32x4 Cv = C[rr * 2 + dt];
#pragma unroll
            for (int rrr = 0; rrr < 4; ++rrr) {
                int row = rr * 16 + quad * 4 + rrr;
                float node = Cv[rrr] / ldsl[h * 32 + row] + bi;
                float o = node * sc + sh;
                ldso[row * 132 + c] = o > 0.f ? o : 0.f;
            }
        }
    }
    __syncthreads();
#pragma unroll
    for (int ps = 0; ps < 4; ++ps) {
        int s = ps * 256 + t;
        int row = s >> 5, c4 = (s & 31) * 4;
        *(float4*)(out + ((size_t)b * N_ + it * IT_ + half * 32 + row) * C_ + c4) =
            *(const float4*)&ldso[row * 132 + c4];
    }
}

// ---------------------------------------------------------------- launch
extern "C" void kernel_launch(void* const* d_in, const int* in_sizes, int n_in,
                              void* d_out, int out_size, void* d_ws, size_t ws_size,
                              hipStream_t stream)
{
    const float* x         = (const float*)d_in[0];
    const float* adj       = (const float*)d_in[1];
    const float* attn_mask = (const float*)d_in[2];
    const float* W         = (const float*)d_in[3];
    const float* a_self    = (const float*)d_in[4];
    const float* a_neigh   = (const float*)d_in[5];
    const float* bias      = (const float*)d_in[6];
    const float* gamma     = (const float*)d_in[7];
    const float* beta      = (const float*)d_in[8];
    const float* mmean     = (const float*)d_in[9];
    const float* mvar      = (const float*)d_in[10];
    float* out = (float*)d_out;

    float* ws = (float*)d_ws;
    unsigned short* featsT = (unsigned short*)ws;                      // 1,048,576 u16
    float* sbuf  = ws + 524288;                                        //    32,768 f
    float* tbuf  = sbuf + (size_t)B_ * H_ * N_;                        //    32,768 f
    float* part  = tbuf + (size_t)B_ * H_ * N_;                        // 8,388,608 f
    float* lpart = part + (size_t)B_ * H_ * ITILES_ * JCA_ * 2048;     //   524,288 f

    hipLaunchKernelGGL(prep_kernel, dim3(B_ * 32), dim3(256), 0, stream,
                       x, W, a_self, a_neigh, featsT, sbuf, tbuf, out);
    hipLaunchKernelGGL(attn_kernel, dim3(B_ * ITILES_ * JCA_), dim3(256), 0, stream,
                       adj, attn_mask, featsT, sbuf, tbuf, part, lpart);
    hipLaunchKernelGGL(final_kernel, dim3(B_ * 64), dim3(256), 0, stream,
                       part, lpart, bias, gamma, beta, mmean, mvar, out);
}